// Round 13
// baseline (1878.798 us; speedup 1.0000x reference)
//
#include <hip/hip_runtime.h>
#include <hip/hip_bf16.h>
#include <math.h>

typedef __bf16 bf16_t;
typedef __bf16 bf16x8 __attribute__((ext_vector_type(8)));
typedef __bf16 bf16x4 __attribute__((ext_vector_type(4)));
typedef float  f32x4  __attribute__((ext_vector_type(4)));

#define NB   16384
#define EDIM 1024
#define FFD  4096
#define NCD  32

__device__ __forceinline__ float gelu_exact(float x) {
    return 0.5f * x * (1.0f + erff(x * 0.70710678118654752f));
}

__device__ __forceinline__ void gload16(const bf16_t* g, bf16_t* l) {
    __builtin_amdgcn_global_load_lds(
        (__attribute__((address_space(1))) void*)(g),
        (__attribute__((address_space(3))) void*)(l),
        16, 0, 0);
}

#define PH_BAR() do { asm volatile("" ::: "memory"); \
                      __builtin_amdgcn_s_barrier();  \
                      asm volatile("" ::: "memory"); } while (0)

enum { EPI_PLAIN = 0, EPI_RESF32 = 1, EPI_GELU = 2, EPI_RESBF16 = 3 };

struct GemmArgs {
    const bf16_t* A0; const bf16_t* A1;
    const bf16_t* B0; const bf16_t* B1;
    const float*  bias0; const float* bias1;
    const void*   res0; const void*  res1;
    bf16_t*       out0; bf16_t*      out1;
};

// ---------------------------------------------------------------------------
// gemmP2 (r13 = r11 geometry + B-direct-from-global):
// 256x128 tile, BK=32, 512 thr (8 waves 4Mx2N, wave tile 64x64), 16x16x32 MFMA.
// r11/r12 pipe audit: LDS port ~85% busy was binding; register wall (acc in
// AGPRs counts against the 512/SIMD pool: 124 total -> 4 waves/SIMD) forbids
// bigger wave tiles. Fix: bv fragments load DIRECT global->reg (16B/lane,
// panel slice 8KB/iter L1-resident, full B panel <=256KB L2-resident) -> LDS
// traffic per block-iter 112KB -> 48KB (A reads 32KB + A staging writes 16KB).
// A staged via global_load_lds into a 4-deep 16KB ring (64KB LDS, prefetch
// distance 3, power-of-2 slot). FIFO ledger: compiler's mandatory pre-MFMA
// vmcnt wait on bv(t) retires stage(t+1),(t+2) (older in FIFO) before each
// barrier -> no explicit mid-loop vmcnt. stage(u+3) overwrites buf[(u-1)&3],
// whose av reads drained (lgkm before MFMA(u-1)) >=1 barrier earlier.
// XOR slot swizzle on A both-sides; r11 traffic-shaped XCD decomposition.
// C[m,n] = sum_k A[m,k]*B[n,k] (+bias) (+epilogue).
// ---------------------------------------------------------------------------
template<int EPI>
__global__ __launch_bounds__(512, 4)
void gemmP2(GemmArgs g, int ldo, int co0, int co1, int M, int N, int K)
{
    __shared__ __align__(128) bf16_t lds[32768];   // 64 KB: 4 bufs x A[256][32]
    char* const ldsb = (char*)lds;

    // ---- traffic-shaped decomposition (r11) ----
    const int nx   = gridDim.x;            // N / 128
    const int ny   = M >> 8;               // M / 256 (per side)
    const int nwg  = nx * gridDim.y;       // total blocks (nx*ny*nsides)
    const int lin  = blockIdx.y * nx + blockIdx.x;
    const int Wx   = nwg >> 3;             // work per XCD (nwg % 8 == 0)
    const int w    = (lin & 7) * Wx + (lin >> 3);
    const int perSide = nx * ny;
    const int side = w / perSide;          // 0 or 1 (always 0 if gridDim.y==ny)
    const int r    = w - side * perSide;
    const int cg   = r / (ny << 3);        // 8-col group (nx % 8 == 0)
    const int tt   = r - cg * (ny << 3);
    const long bm  = (long)(tt >> 3) * 256;
    const long bn  = (long)((cg << 3) + (tt & 7)) * 128;

    const bf16_t* __restrict__ A    = side ? g.A1   : g.A0;
    const bf16_t* __restrict__ Bw   = side ? g.B1   : g.B0;
    const float*  __restrict__ bias = side ? g.bias1: g.bias0;
    const void*   __restrict__ resid= side ? g.res1 : g.res0;
    bf16_t*       __restrict__ out  = side ? g.out1 : g.out0;
    const int coloff = side ? co1 : co0;

    const int tid = threadIdx.x, lane = tid & 63, wave = tid >> 6;
    const int wm = wave >> 1, wn = wave & 1;      // 4M x 2N wave grid
    const int fr = lane & 15, ks = lane >> 4;
    const int csw = ((ks ^ (fr & 3)) << 4);       // swizzled 16B slot in 64B row

    // A staging: chunk p covers row p>>2, phys slot p&3 holding logical
    // slot (p&3)^((p>>2)&3); global source column pre-swizzled to match.
    const int sl = ((tid & 3) ^ ((tid >> 2) & 3)) * 8;
    const bf16_t* gA = A + (bm + (tid >> 2)) * (long)K + sl;   // rows 0..127

    // B direct: 4 fragment-row element indexes (32-bit; max ~16.5M < 2^31)
    int bidx[4];
    #pragma unroll
    for (int ni = 0; ni < 4; ++ni)
        bidx[ni] = (int)((bn + wn * 64 + ni * 16 + fr) * (long)K) + ks * 8;

    const int nt = K >> 5;
    auto STAGE = [&](int t) {                      // 2 x gload_lds (A halves)
        const int bufo = (t & 3) * 16384;
        const long kt = (long)t << 5;
        gload16(gA + kt,                  (bf16_t*)(ldsb + bufo + wave * 1024));
        gload16(gA + kt + 128 * (long)K,  (bf16_t*)(ldsb + bufo + 8192 + wave * 1024));
    };

    f32x4 acc[4][4] = {};

    STAGE(0);
    STAGE(1);
    STAGE(2);
    asm volatile("s_waitcnt vmcnt(4)" ::: "memory");   // stage(0) retired
    PH_BAR();

    for (int t = 0; t < nt; ++t) {
        const char* base = ldsb + (t & 3) * 16384;
        const int kb = t << 5;
        bf16x8 av[4], bv[4];
        #pragma unroll
        for (int i = 0; i < 4; ++i)
            bv[i] = *(const bf16x8*)(Bw + bidx[i] + kb);
        #pragma unroll
        for (int i = 0; i < 4; ++i)
            av[i] = *(const bf16x8*)(base + (wm * 64 + i * 16 + fr) * 64 + csw);
        if (t + 3 < nt) STAGE(t + 3);
        __builtin_amdgcn_s_setprio(1);
        #pragma unroll
        for (int mi = 0; mi < 4; ++mi)
            #pragma unroll
            for (int ni = 0; ni < 4; ++ni)
                acc[mi][ni] = __builtin_amdgcn_mfma_f32_16x16x32_bf16(
                                  av[mi], bv[ni], acc[mi][ni], 0, 0, 0);
        __builtin_amdgcn_s_setprio(0);
        // no explicit vmcnt: the compiler's pre-MFMA wait on bv(t) retired
        // stage(t+1)/(t+2) (older in the vmcnt FIFO); barrier publishes them.
        PH_BAR();
    }

    // epilogue: C/D layout col=lane&15, row=(lane>>4)*4+reg
    const int rq = (lane >> 4) * 4;
    #pragma unroll
    for (int mi = 0; mi < 4; ++mi) {
        #pragma unroll
        for (int ni = 0; ni < 4; ++ni) {
            const long n = bn + wn * 64 + ni * 16 + fr;
            const float bval = bias ? bias[n] : 0.0f;
            #pragma unroll
            for (int r2 = 0; r2 < 4; ++r2) {
                const long m = bm + wm * 64 + mi * 16 + rq + r2;
                float v = acc[mi][ni][r2] + bval;
                if (EPI == EPI_RESF32)  v += ((const float*)resid)[m * (long)N + n];
                if (EPI == EPI_RESBF16) v += (float)((const bf16_t*)resid)[m * (long)N + n];
                if (EPI == EPI_GELU)    v = gelu_exact(v);
                out[m * (long)ldo + coloff + n] = (bf16_t)v;
            }
        }
    }
}

// ---------------------------------------------------------------------------
// Final head GEMM with MFMA: out[m, 0..31] = U[m,:]@W2.T + b2, f32 out.
// ---------------------------------------------------------------------------
__global__ __launch_bounds__(256)
void final_mfma(const bf16_t* __restrict__ U, const bf16_t* __restrict__ W2,
                const float* __restrict__ b2, float* __restrict__ out)
{
    __shared__ bf16_t sA[128 * 32];
    __shared__ bf16_t sB[32 * 32];
    const int tid = threadIdx.x, lane = tid & 63, wave = tid >> 6;
    const long bm = (long)blockIdx.x * 128;
    const int srow = lane >> 2, scol = (lane & 3) * 8;

    const bf16_t* gA = U + (bm + wave * 32 + srow) * (long)EDIM + scol;
    bf16_t* lA = sA + wave * 32 * 32;
    const bf16_t* gB = W2 + ((long)wave * 16 + srow) * EDIM + scol;
    bf16_t* lB = sB + wave * 16 * 32;

    const int fr = lane & 15, fk = (lane >> 4) * 8;
    const bf16_t* rA = sA + (wave * 32 + fr) * 32 + fk;
    const bf16_t* rB = sB + fr * 32 + fk;

    f32x4 acc[2][2] = {};
    for (int kt = 0; kt < EDIM; kt += 32) {
        gload16(gA + kt,             lA);
        gload16(gA + kt + 16 * EDIM, lA + 16 * 32);
        if (wave < 2) gload16(gB + kt, lB);
        __syncthreads();
        bf16x8 av[2], bv[2];
        av[0] = *(const bf16x8*)(rA);
        av[1] = *(const bf16x8*)(rA + 16 * 32);
        bv[0] = *(const bf16x8*)(rB);
        bv[1] = *(const bf16x8*)(rB + 16 * 32);
        #pragma unroll
        for (int mi = 0; mi < 2; ++mi)
            #pragma unroll
            for (int ni = 0; ni < 2; ++ni)
                acc[mi][ni] = __builtin_amdgcn_mfma_f32_16x16x32_bf16(
                                  av[mi], bv[ni], acc[mi][ni], 0, 0, 0);
        __syncthreads();
    }
    const int rq = (lane >> 4) * 4;
    #pragma unroll
    for (int mi = 0; mi < 2; ++mi)
        #pragma unroll
        for (int ni = 0; ni < 2; ++ni) {
            const int n = ni * 16 + fr;
            const float bval = b2[n];
            #pragma unroll
            for (int r = 0; r < 4; ++r) {
                const long m = bm + wave * 32 + mi * 16 + rq + r;
                out[m * NCD + n] = acc[mi][ni][r] + bval;
            }
        }
}

// ---------------------------------------------------------------------------
// LayerNorms / elementwise helpers
// ---------------------------------------------------------------------------
__global__ __launch_bounds__(256)
void ln_f32(const float* __restrict__ X, const float* __restrict__ g,
            const float* __restrict__ b, bf16_t* __restrict__ out)
{
    const long row = blockIdx.x;
    const int t = threadIdx.x;
    f32x4 x = ((const f32x4*)(X + row * EDIM))[t];
    float s = x[0] + x[1] + x[2] + x[3];
    float q = x[0]*x[0] + x[1]*x[1] + x[2]*x[2] + x[3]*x[3];
    #pragma unroll
    for (int off = 32; off; off >>= 1) { s += __shfl_xor(s, off); q += __shfl_xor(q, off); }
    __shared__ float red[8];
    if ((t & 63) == 0) { red[(t >> 6) * 2] = s; red[(t >> 6) * 2 + 1] = q; }
    __syncthreads();
    s = red[0] + red[2] + red[4] + red[6];
    q = red[1] + red[3] + red[5] + red[7];
    const float mean = s * (1.0f / EDIM);
    const float rs = rsqrtf(q * (1.0f / EDIM) - mean * mean + 1e-5f);
    f32x4 gg = ((const f32x4*)g)[t];
    f32x4 bb = ((const f32x4*)b)[t];
    bf16x4 o;
    #pragma unroll
    for (int j = 0; j < 4; ++j) o[j] = (bf16_t)((x[j] - mean) * rs * gg[j] + bb[j]);
    ((bf16x4*)(out + row * EDIM))[t] = o;
}

__global__ __launch_bounds__(256)
void ln_cat(const bf16_t* __restrict__ X, const float* __restrict__ g,
            const float* __restrict__ b, bf16_t* __restrict__ out)
{
    const long row = blockIdx.x;
    const int t = threadIdx.x;
    bf16x8 xv = ((const bf16x8*)(X + row * 2048))[t];
    float xf[8];
    float s = 0.f, q = 0.f;
    #pragma unroll
    for (int j = 0; j < 8; ++j) { xf[j] = (float)xv[j]; s += xf[j]; q += xf[j] * xf[j]; }
    #pragma unroll
    for (int off = 32; off; off >>= 1) { s += __shfl_xor(s, off); q += __shfl_xor(q, off); }
    __shared__ float red[8];
    if ((t & 63) == 0) { red[(t >> 6) * 2] = s; red[(t >> 6) * 2 + 1] = q; }
    __syncthreads();
    s = red[0] + red[2] + red[4] + red[6];
    q = red[1] + red[3] + red[5] + red[7];
    const float mean = s * (1.0f / 2048);
    const float rs = rsqrtf(q * (1.0f / 2048) - mean * mean + 1e-5f);
    f32x4 g0 = ((const f32x4*)g)[2 * t], g1 = ((const f32x4*)g)[2 * t + 1];
    f32x4 b0 = ((const f32x4*)b)[2 * t], b1 = ((const f32x4*)b)[2 * t + 1];
    bf16x8 o;
    #pragma unroll
    for (int j = 0; j < 4; ++j) o[j]     = (bf16_t)((xf[j]     - mean) * rs * g0[j] + b0[j]);
    #pragma unroll
    for (int j = 0; j < 4; ++j) o[4 + j] = (bf16_t)((xf[4 + j] - mean) * rs * g1[j] + b1[j]);
    ((bf16x8*)(out + row * 2048))[t] = o;
}

__global__ __launch_bounds__(256)
void ln_gelu(const bf16_t* __restrict__ X, const float* __restrict__ g,
             const float* __restrict__ b, bf16_t* __restrict__ out)
{
    const long row = blockIdx.x;
    const int t = threadIdx.x;
    bf16x4 xv = ((const bf16x4*)(X + row * EDIM))[t];
    float xf[4];
    float s = 0.f, q = 0.f;
    #pragma unroll
    for (int j = 0; j < 4; ++j) { xf[j] = (float)xv[j]; s += xf[j]; q += xf[j] * xf[j]; }
    #pragma unroll
    for (int off = 32; off; off >>= 1) { s += __shfl_xor(s, off); q += __shfl_xor(q, off); }
    __shared__ float red[8];
    if ((t & 63) == 0) { red[(t >> 6) * 2] = s; red[(t >> 6) * 2 + 1] = q; }
    __syncthreads();
    s = red[0] + red[2] + red[4] + red[6];
    q = red[1] + red[3] + red[5] + red[7];
    const float mean = s * (1.0f / EDIM);
    const float rs = rsqrtf(q * (1.0f / EDIM) - mean * mean + 1e-5f);
    f32x4 gg = ((const f32x4*)g)[t];
    f32x4 bb = ((const f32x4*)b)[t];
    bf16x4 o;
    #pragma unroll
    for (int j = 0; j < 4; ++j)
        o[j] = (bf16_t)gelu_exact((xf[j] - mean) * rs * gg[j] + bb[j]);
    ((bf16x4*)(out + row * EDIM))[t] = o;
}

__global__ void f2b(const float* __restrict__ in, bf16_t* __restrict__ out, long n4)
{
    long i = (long)blockIdx.x * blockDim.x + threadIdx.x;
    const long stride = (long)gridDim.x * blockDim.x;
    for (; i < n4; i += stride) {
        f32x4 v = ((const f32x4*)in)[i];
        bf16x4 o;
        #pragma unroll
        for (int j = 0; j < 4; ++j) o[j] = (bf16_t)v[j];
        ((bf16x4*)out)[i] = o;
    }
}

__global__ void tconv(const float* __restrict__ in, bf16_t* __restrict__ out)
{
    const long x = (long)blockIdx.x * 256 + threadIdx.x;
    const int k = (int)(x & (EDIM - 1));
    const int j = (int)(x >> 10);
    out[(long)j * EDIM + k] = (bf16_t)in[(long)k * EDIM + j];
}

__global__ __launch_bounds__(256)
void bcomb_k(const float* __restrict__ Wo, const float* __restrict__ bv,
             const float* __restrict__ bo, float* __restrict__ bc)
{
    const int i = blockIdx.x;
    const int t = threadIdx.x;
    f32x4 w = ((const f32x4*)(Wo + (long)i * EDIM))[t];
    f32x4 v = ((const f32x4*)bv)[t];
    float s = w[0]*v[0] + w[1]*v[1] + w[2]*v[2] + w[3]*v[3];
    #pragma unroll
    for (int off = 32; off; off >>= 1) s += __shfl_xor(s, off);
    __shared__ float red[4];
    if ((t & 63) == 0) red[t >> 6] = s;
    __syncthreads();
    if (t == 0) bc[i] = red[0] + red[1] + red[2] + red[3] + bo[i];
}

extern "C" void kernel_launch(void* const* d_in, const int* in_sizes, int n_in,
                              void* d_out, int out_size, void* d_ws, size_t ws_size,
                              hipStream_t stream)
{
    const float* lc_cls   = (const float*)d_in[0];
    const float* tab_emb  = (const float*)d_in[1];
    const float* ln_lc_g  = (const float*)d_in[2];
    const float* ln_lc_b  = (const float*)d_in[3];
    const float* ln_tab_g = (const float*)d_in[4];
    const float* ln_tab_b = (const float*)d_in[5];
    const float* alc_Wv   = (const float*)d_in[8];
    const float* alc_bv   = (const float*)d_in[11];
    const float* alc_Wo   = (const float*)d_in[12];
    const float* alc_bo   = (const float*)d_in[13];
    const float* atab_Wv  = (const float*)d_in[16];
    const float* atab_bv  = (const float*)d_in[19];
    const float* atab_Wo  = (const float*)d_in[20];
    const float* atab_bo  = (const float*)d_in[21];
    const float* flc_W1   = (const float*)d_in[22];
    const float* flc_b1   = (const float*)d_in[23];
    const float* flc_W2   = (const float*)d_in[24];
    const float* flc_b2   = (const float*)d_in[25];
    const float* ftab_W1  = (const float*)d_in[26];
    const float* ftab_b1  = (const float*)d_in[27];
    const float* ftab_W2  = (const float*)d_in[28];
    const float* ftab_b2  = (const float*)d_in[29];
    const float* on_g     = (const float*)d_in[30];
    const float* on_b     = (const float*)d_in[31];
    const float* c_W1     = (const float*)d_in[32];
    const float* c_b1     = (const float*)d_in[33];
    const float* c_ln_g   = (const float*)d_in[34];
    const float* c_ln_b   = (const float*)d_in[35];
    const float* c_W2     = (const float*)d_in[36];
    const float* c_b2     = (const float*)d_in[37];

    char* ws = (char*)d_ws;
    size_t woff = 0;
    auto walloc = [&](size_t bytes) {
        void* p = ws + woff;
        woff += (bytes + 255) & ~(size_t)255;
        return p;
    };
    // persistent bf16 weights (~38.2 MiB)
    bf16_t* Wc_lc  = (bf16_t*)walloc((size_t)EDIM * EDIM * 2);
    bf16_t* Wc_tab = (bf16_t*)walloc((size_t)EDIM * EDIM * 2);
    bf16_t* W1lc_b = (bf16_t*)walloc((size_t)FFD * EDIM * 2);
    bf16_t* W2lc_b = (bf16_t*)walloc((size_t)EDIM * FFD * 2);
    bf16_t* W1tab_b= (bf16_t*)walloc((size_t)FFD * EDIM * 2);
    bf16_t* W2tab_b= (bf16_t*)walloc((size_t)EDIM * FFD * 2);
    bf16_t* cW1_b  = (bf16_t*)walloc((size_t)EDIM * 2 * EDIM * 2);
    bf16_t* cW2_b  = (bf16_t*)walloc((size_t)NCD * EDIM * 2);
    float*  bc_lc  = (float*)walloc(EDIM * 4);
    float*  bc_tab = (float*)walloc(EDIM * 4);

    char* arena = ws + woff;
    const size_t arena_sz = (ws_size > woff) ? (ws_size - woff) : 0;

    // SB rows per super-chunk; arena need = SB*24576 bytes:
    //   cat (SB*4096, aliases lc_n|tab_n) | lc_x | tab_x | hbuf0 | hbuf1
    int SB = NB;
    while (SB > 256 && (size_t)SB * 24576 > arena_sz) SB >>= 1;
    if ((size_t)SB * 24576 > arena_sz) return;

    const size_t S2 = (size_t)SB * 2048;
    bf16_t* lc_n  = (bf16_t*)(arena);
    bf16_t* tab_n = (bf16_t*)(arena + S2);
    bf16_t* cat   = (bf16_t*)(arena);
    bf16_t* lc_x  = (bf16_t*)(arena + 2 * S2);
    bf16_t* tab_x = (bf16_t*)(arena + 3 * S2);
    bf16_t* hbuf0 = (bf16_t*)(arena + 4 * S2);
    bf16_t* hbuf1 = (bf16_t*)(arena + 8 * S2);
    bf16_t* tbuf  = lc_x;
    bf16_t* ubuf  = tab_x;

    // weight-prep temps (first 8 MiB of arena; used before activations exist)
    bf16_t* Wo_lc_b  = (bf16_t*)(arena);
    bf16_t* Wo_tab_b = (bf16_t*)(arena + (size_t)2 * 1024 * 1024);
    bf16_t* WvT_lc   = (bf16_t*)(arena + (size_t)4 * 1024 * 1024);
    bf16_t* WvT_tab  = (bf16_t*)(arena + (size_t)6 * 1024 * 1024);

    // ---- weight prep ----
    f2b<<<512, 256, 0, stream>>>(alc_Wo,  Wo_lc_b,  (long)EDIM * EDIM / 4);
    f2b<<<512, 256, 0, stream>>>(atab_Wo, Wo_tab_b, (long)EDIM * EDIM / 4);
    tconv<<<EDIM * EDIM / 256, 256, 0, stream>>>(alc_Wv,  WvT_lc);
    tconv<<<EDIM * EDIM / 256, 256, 0, stream>>>(atab_Wv, WvT_tab);
    f2b<<<2048, 256, 0, stream>>>(flc_W1,  W1lc_b,  (long)FFD * EDIM / 4);
    f2b<<<2048, 256, 0, stream>>>(flc_W2,  W2lc_b,  (long)EDIM * FFD / 4);
    f2b<<<2048, 256, 0, stream>>>(ftab_W1, W1tab_b, (long)FFD * EDIM / 4);
    f2b<<<2048, 256, 0, stream>>>(ftab_W2, W2tab_b, (long)EDIM * FFD / 4);
    f2b<<<1024, 256, 0, stream>>>(c_W1,    cW1_b,   (long)EDIM * 2 * EDIM / 4);
    f2b<<<32,   256, 0, stream>>>(c_W2,    cW2_b,   (long)NCD * EDIM / 4);
    bcomb_k<<<EDIM, 256, 0, stream>>>(alc_Wo,  alc_bv,  alc_bo,  bc_lc);
    bcomb_k<<<EDIM, 256, 0, stream>>>(atab_Wo, atab_bv, atab_bo, bc_tab);
    {   // Wcomb = Wo @ Wv (softmax over a single key == 1)
        GemmArgs ga = { Wo_lc_b, Wo_tab_b, WvT_lc, WvT_tab,
                        nullptr, nullptr, nullptr, nullptr, Wc_lc, Wc_tab };
        gemmP2<EPI_PLAIN><<<dim3(EDIM/128, (EDIM/256) * 2), 512, 0, stream>>>(
            ga, EDIM, 0, 0, EDIM, EDIM, EDIM);
    }

    // ---- batch loop ----
    for (long c0 = 0; c0 < NB; c0 += SB) {
        const float* lcI  = lc_cls  + c0 * EDIM;
        const float* tabI = tab_emb + c0 * EDIM;

        ln_f32<<<SB, 256, 0, stream>>>(lcI,  ln_lc_g,  ln_lc_b,  lc_n);
        ln_f32<<<SB, 256, 0, stream>>>(tabI, ln_tab_g, ln_tab_b, tab_n);

        {   // cross = resid + x_n @ Wcomb.T + bcomb
            GemmArgs ga = { tab_n, lc_n, Wc_lc, Wc_tab, bc_lc, bc_tab,
                            lcI, tabI, lc_x, tab_x };
            gemmP2<EPI_RESF32><<<dim3(EDIM/128, (SB/256) * 2), 512, 0, stream>>>(
                ga, EDIM, 0, 0, SB, EDIM, EDIM);
        }
        {   // FFN1: h = gelu(x @ W1.T + b1)
            GemmArgs ga = { lc_x, tab_x, W1lc_b, W1tab_b, flc_b1, ftab_b1,
                            nullptr, nullptr, hbuf0, hbuf1 };
            gemmP2<EPI_GELU><<<dim3(FFD/128, (SB/256) * 2), 512, 0, stream>>>(
                ga, FFD, 0, 0, SB, FFD, EDIM);
        }
        {   // FFN2: cat half = x + h @ W2.T + b2
            GemmArgs ga = { hbuf0, hbuf1, W2lc_b, W2tab_b, flc_b2, ftab_b2,
                            lc_x, tab_x, cat, cat };
            gemmP2<EPI_RESBF16><<<dim3(EDIM/128, (SB/256) * 2), 512, 0, stream>>>(
                ga, 2 * EDIM, 0, EDIM, SB, EDIM, FFD);
        }

        // output LN over 2048 (in place)
        ln_cat<<<SB, 256, 0, stream>>>(cat, on_g, on_b, cat);

        {   // classifier GEMM (K=2048, single side: gridDim.y == ny)
            GemmArgs ga = { cat, cat, cW1_b, cW1_b, c_b1, c_b1,
                            nullptr, nullptr, tbuf, tbuf };
            gemmP2<EPI_PLAIN><<<dim3(EDIM/128, SB/256), 512, 0, stream>>>(
                ga, EDIM, 0, 0, SB, EDIM, 2 * EDIM);
        }
        ln_gelu<<<SB, 256, 0, stream>>>(tbuf, c_ln_g, c_ln_b, ubuf);
        final_mfma<<<SB / 128, 256, 0, stream>>>(ubuf, cW2_b, c_b2,
                                                 (float*)d_out + c0 * NCD);
    }
}

// Round 14
// 1027.510 us; speedup vs baseline: 1.8285x; 1.8285x over previous
//
#include <hip/hip_runtime.h>
#include <hip/hip_bf16.h>
#include <math.h>

typedef __bf16 bf16_t;
typedef __bf16 bf16x8 __attribute__((ext_vector_type(8)));
typedef __bf16 bf16x4 __attribute__((ext_vector_type(4)));
typedef float  f32x4  __attribute__((ext_vector_type(4)));

#define NB   16384
#define EDIM 1024
#define FFD  4096
#define NCD  32

__device__ __forceinline__ float gelu_exact(float x) {
    return 0.5f * x * (1.0f + erff(x * 0.70710678118654752f));
}

__device__ __forceinline__ void gload16(const bf16_t* g, bf16_t* l) {
    __builtin_amdgcn_global_load_lds(
        (__attribute__((address_space(1))) void*)(g),
        (__attribute__((address_space(3))) void*)(l),
        16, 0, 0);
}

#define PH_BAR() do { asm volatile("" ::: "memory"); \
                      __builtin_amdgcn_s_barrier();  \
                      asm volatile("" ::: "memory"); } while (0)

enum { EPI_PLAIN = 0, EPI_RESF32 = 1, EPI_GELU = 2, EPI_RESBF16 = 3 };

struct GemmArgs {
    const bf16_t* A0; const bf16_t* A1;
    const bf16_t* B0; const bf16_t* B1;
    const float*  bias0; const float* bias1;
    const void*   res0; const void*  res1;
    bf16_t*       out0; bf16_t*      out1;
};

// ---------------------------------------------------------------------------
// gemmP2 (r14 = r11 verbatim, the measured optimum of rounds 3-13):
// 256x128 tile, BK=32, 512 thr (8 waves 4Mx2N, wave tile 64x64), 16x16x32 MFMA.
// 3-deep LDS ring (72 KB), counted vmcnt(3) prefetch-2 (vmcnt(0) only in the
// 2-iter tail — r5 race lesson), 2 blocks/CU x 4 waves/SIMD (60 arch VGPR +
// 64 AGPR = 124 <= 128), XOR slot swizzle both-sides (r9: 32x32 shape breaks
// it), r11 traffic-shaped XCD decomposition (single-side contiguous ranges,
// 8-col-group order: FETCH 266->118 MB). A/B'd and rejected: 8-phase (null at
// this occupancy), setprio (null, r10), 32x32x16 (3x bank conflicts, r9),
// 128x64 wave tile (register wall -> 2 waves/SIMD, r12), B-direct-global
// (uncovered L2 latency + 16-line scatter, r13).
// C[m,n] = sum_k A[m,k]*B[n,k] (+bias) (+epilogue).
// ---------------------------------------------------------------------------
template<int EPI>
__global__ __launch_bounds__(512, 4)
void gemmP2(GemmArgs g, int ldo, int co0, int co1, int M, int N, int K)
{
    __shared__ __align__(128) bf16_t lds[36864];   // 72 KB: 3 bufs x (A 16K | B 8K)
    char* const ldsb = (char*)lds;

    // ---- traffic-shaped decomposition (r11) ----
    const int nx   = gridDim.x;            // N / 128
    const int ny   = M >> 8;               // M / 256 (per side)
    const int nwg  = nx * gridDim.y;       // total blocks (nx*ny*nsides)
    const int lin  = blockIdx.y * nx + blockIdx.x;
    const int Wx   = nwg >> 3;             // work per XCD (nwg % 8 == 0)
    const int w    = (lin & 7) * Wx + (lin >> 3);
    const int perSide = nx * ny;
    const int side = w / perSide;          // 0 or 1 (always 0 if gridDim.y==ny)
    const int r    = w - side * perSide;
    const int cg   = r / (ny << 3);        // 8-col group (nx % 8 == 0)
    const int tt   = r - cg * (ny << 3);
    const long bm  = (long)(tt >> 3) * 256;
    const long bn  = (long)((cg << 3) + (tt & 7)) * 128;

    const bf16_t* __restrict__ A    = side ? g.A1   : g.A0;
    const bf16_t* __restrict__ Bw   = side ? g.B1   : g.B0;
    const float*  __restrict__ bias = side ? g.bias1: g.bias0;
    const void*   __restrict__ resid= side ? g.res1 : g.res0;
    bf16_t*       __restrict__ out  = side ? g.out1 : g.out0;
    const int coloff = side ? co1 : co0;

    const int tid = threadIdx.x, lane = tid & 63, wave = tid >> 6;
    const int wm = wave >> 1, wn = wave & 1;      // 4M x 2N wave grid
    const int fr = lane & 15, ks = lane >> 4;
    const int csw = ((ks ^ (fr & 3)) << 4);       // swizzled 16B slot in 64B row

    // staging: chunk p covers row p>>2, phys slot p&3 holding logical
    // slot (p&3)^((p>>2)&3); global source column pre-swizzled to match.
    const int sl = ((tid & 3) ^ ((tid >> 2) & 3)) * 8;
    const bf16_t* gA = A  + (bm + (tid >> 2)) * (long)K + sl;  // rows 0..127
    const bf16_t* gB = Bw + (bn + (tid >> 2)) * (long)K + sl;
    bf16_t* const dA0 = (bf16_t*)(ldsb + wave * 1024);          // + buf*24576
    bf16_t* const dA1 = (bf16_t*)(ldsb + 8192  + wave * 1024);
    bf16_t* const dB  = (bf16_t*)(ldsb + 16384 + wave * 1024);

    const int nt = K >> 5;
    auto STAGE = [&](int t) {                      // 3 x gload_lds
        const int bufo = (t % 3) * 24576;
        const long kt = (long)t << 5;
        gload16(gA + kt,                 (bf16_t*)((char*)dA0 + bufo));
        gload16(gA + kt + 128 * (long)K, (bf16_t*)((char*)dA1 + bufo));
        gload16(gB + kt,                 (bf16_t*)((char*)dB  + bufo));
    };

    f32x4 acc[4][4] = {};

    STAGE(0);
    STAGE(1);
    asm volatile("s_waitcnt vmcnt(3)" ::: "memory");   // tile 0 complete
    PH_BAR();

    for (int t = 0; t < nt; ++t) {
        const char* base = ldsb + (t % 3) * 24576;
        bf16x8 av[4], bv[4];
        #pragma unroll
        for (int i = 0; i < 4; ++i) {
            av[i] = *(const bf16x8*)(base + (wm * 64 + i * 16 + fr) * 64 + csw);
            bv[i] = *(const bf16x8*)(base + 16384 + (wn * 64 + i * 16 + fr) * 64 + csw);
        }
        if (t + 2 < nt) STAGE(t + 2);
        __builtin_amdgcn_s_setprio(1);
        #pragma unroll
        for (int mi = 0; mi < 4; ++mi)
            #pragma unroll
            for (int ni = 0; ni < 4; ++ni)
                acc[mi][ni] = __builtin_amdgcn_mfma_f32_16x16x32_bf16(
                                  av[mi], bv[ni], acc[mi][ni], 0, 0, 0);
        __builtin_amdgcn_s_setprio(0);
        // counted wait: retires tile t+1 (issued >=1 iter ago); tile t+2 stays
        // in flight across the barrier. Tail must drain fully.
        if (t + 2 < nt) { asm volatile("s_waitcnt vmcnt(3)" ::: "memory"); }
        else            { asm volatile("s_waitcnt vmcnt(0)" ::: "memory"); }
        PH_BAR();
    }

    // epilogue: C/D layout col=lane&15, row=(lane>>4)*4+reg
    const int rq = (lane >> 4) * 4;
    #pragma unroll
    for (int mi = 0; mi < 4; ++mi) {
        #pragma unroll
        for (int ni = 0; ni < 4; ++ni) {
            const long n = bn + wn * 64 + ni * 16 + fr;
            const float bval = bias ? bias[n] : 0.0f;
            #pragma unroll
            for (int r2 = 0; r2 < 4; ++r2) {
                const long m = bm + wm * 64 + mi * 16 + rq + r2;
                float v = acc[mi][ni][r2] + bval;
                if (EPI == EPI_RESF32)  v += ((const float*)resid)[m * (long)N + n];
                if (EPI == EPI_RESBF16) v += (float)((const bf16_t*)resid)[m * (long)N + n];
                if (EPI == EPI_GELU)    v = gelu_exact(v);
                out[m * (long)ldo + coloff + n] = (bf16_t)v;
            }
        }
    }
}

// ---------------------------------------------------------------------------
// Final head GEMM with MFMA: out[m, 0..31] = U[m,:]@W2.T + b2, f32 out.
// ---------------------------------------------------------------------------
__global__ __launch_bounds__(256)
void final_mfma(const bf16_t* __restrict__ U, const bf16_t* __restrict__ W2,
                const float* __restrict__ b2, float* __restrict__ out)
{
    __shared__ bf16_t sA[128 * 32];
    __shared__ bf16_t sB[32 * 32];
    const int tid = threadIdx.x, lane = tid & 63, wave = tid >> 6;
    const long bm = (long)blockIdx.x * 128;
    const int srow = lane >> 2, scol = (lane & 3) * 8;

    const bf16_t* gA = U + (bm + wave * 32 + srow) * (long)EDIM + scol;
    bf16_t* lA = sA + wave * 32 * 32;
    const bf16_t* gB = W2 + ((long)wave * 16 + srow) * EDIM + scol;
    bf16_t* lB = sB + wave * 16 * 32;

    const int fr = lane & 15, fk = (lane >> 4) * 8;
    const bf16_t* rA = sA + (wave * 32 + fr) * 32 + fk;
    const bf16_t* rB = sB + fr * 32 + fk;

    f32x4 acc[2][2] = {};
    for (int kt = 0; kt < EDIM; kt += 32) {
        gload16(gA + kt,             lA);
        gload16(gA + kt + 16 * EDIM, lA + 16 * 32);
        if (wave < 2) gload16(gB + kt, lB);
        __syncthreads();
        bf16x8 av[2], bv[2];
        av[0] = *(const bf16x8*)(rA);
        av[1] = *(const bf16x8*)(rA + 16 * 32);
        bv[0] = *(const bf16x8*)(rB);
        bv[1] = *(const bf16x8*)(rB + 16 * 32);
        #pragma unroll
        for (int mi = 0; mi < 2; ++mi)
            #pragma unroll
            for (int ni = 0; ni < 2; ++ni)
                acc[mi][ni] = __builtin_amdgcn_mfma_f32_16x16x32_bf16(
                                  av[mi], bv[ni], acc[mi][ni], 0, 0, 0);
        __syncthreads();
    }
    const int rq = (lane >> 4) * 4;
    #pragma unroll
    for (int mi = 0; mi < 2; ++mi)
        #pragma unroll
        for (int ni = 0; ni < 2; ++ni) {
            const int n = ni * 16 + fr;
            const float bval = b2[n];
            #pragma unroll
            for (int r = 0; r < 4; ++r) {
                const long m = bm + wave * 32 + mi * 16 + rq + r;
                out[m * NCD + n] = acc[mi][ni][r] + bval;
            }
        }
}

// ---------------------------------------------------------------------------
// LayerNorms / elementwise helpers
// ---------------------------------------------------------------------------
// dual-side LN over 1024 fp32 -> bf16 (one launch for lc and tab)
__global__ __launch_bounds__(256)
void ln2_f32(const float* __restrict__ X0, const float* __restrict__ g0,
             const float* __restrict__ b0, bf16_t* __restrict__ o0,
             const float* __restrict__ X1, const float* __restrict__ g1,
             const float* __restrict__ b1, bf16_t* __restrict__ o1)
{
    const long row = blockIdx.x;
    const int t = threadIdx.x;
    const float* X = blockIdx.y ? X1 : X0;
    const float* g = blockIdx.y ? g1 : g0;
    const float* b = blockIdx.y ? b1 : b0;
    bf16_t* out    = blockIdx.y ? o1 : o0;
    f32x4 x = ((const f32x4*)(X + row * EDIM))[t];
    float s = x[0] + x[1] + x[2] + x[3];
    float q = x[0]*x[0] + x[1]*x[1] + x[2]*x[2] + x[3]*x[3];
    #pragma unroll
    for (int off = 32; off; off >>= 1) { s += __shfl_xor(s, off); q += __shfl_xor(q, off); }
    __shared__ float red[8];
    if ((t & 63) == 0) { red[(t >> 6) * 2] = s; red[(t >> 6) * 2 + 1] = q; }
    __syncthreads();
    s = red[0] + red[2] + red[4] + red[6];
    q = red[1] + red[3] + red[5] + red[7];
    const float mean = s * (1.0f / EDIM);
    const float rs = rsqrtf(q * (1.0f / EDIM) - mean * mean + 1e-5f);
    f32x4 gg = ((const f32x4*)g)[t];
    f32x4 bb = ((const f32x4*)b)[t];
    bf16x4 o;
    #pragma unroll
    for (int j = 0; j < 4; ++j) o[j] = (bf16_t)((x[j] - mean) * rs * gg[j] + bb[j]);
    ((bf16x4*)(out + row * EDIM))[t] = o;
}

__global__ __launch_bounds__(256)
void ln_cat(const bf16_t* __restrict__ X, const float* __restrict__ g,
            const float* __restrict__ b, bf16_t* __restrict__ out)
{
    const long row = blockIdx.x;
    const int t = threadIdx.x;
    bf16x8 xv = ((const bf16x8*)(X + row * 2048))[t];
    float xf[8];
    float s = 0.f, q = 0.f;
    #pragma unroll
    for (int j = 0; j < 8; ++j) { xf[j] = (float)xv[j]; s += xf[j]; q += xf[j] * xf[j]; }
    #pragma unroll
    for (int off = 32; off; off >>= 1) { s += __shfl_xor(s, off); q += __shfl_xor(q, off); }
    __shared__ float red[8];
    if ((t & 63) == 0) { red[(t >> 6) * 2] = s; red[(t >> 6) * 2 + 1] = q; }
    __syncthreads();
    s = red[0] + red[2] + red[4] + red[6];
    q = red[1] + red[3] + red[5] + red[7];
    const float mean = s * (1.0f / 2048);
    const float rs = rsqrtf(q * (1.0f / 2048) - mean * mean + 1e-5f);
    f32x4 g0 = ((const f32x4*)g)[2 * t], g1 = ((const f32x4*)g)[2 * t + 1];
    f32x4 b0 = ((const f32x4*)b)[2 * t], b1 = ((const f32x4*)b)[2 * t + 1];
    bf16x8 o;
    #pragma unroll
    for (int j = 0; j < 4; ++j) o[j]     = (bf16_t)((xf[j]     - mean) * rs * g0[j] + b0[j]);
    #pragma unroll
    for (int j = 0; j < 4; ++j) o[4 + j] = (bf16_t)((xf[4 + j] - mean) * rs * g1[j] + b1[j]);
    ((bf16x8*)(out + row * 2048))[t] = o;
}

__global__ __launch_bounds__(256)
void ln_gelu(const bf16_t* __restrict__ X, const float* __restrict__ g,
             const float* __restrict__ b, bf16_t* __restrict__ out)
{
    const long row = blockIdx.x;
    const int t = threadIdx.x;
    bf16x4 xv = ((const bf16x4*)(X + row * EDIM))[t];
    float xf[4];
    float s = 0.f, q = 0.f;
    #pragma unroll
    for (int j = 0; j < 4; ++j) { xf[j] = (float)xv[j]; s += xf[j]; q += xf[j] * xf[j]; }
    #pragma unroll
    for (int off = 32; off; off >>= 1) { s += __shfl_xor(s, off); q += __shfl_xor(q, off); }
    __shared__ float red[8];
    if ((t & 63) == 0) { red[(t >> 6) * 2] = s; red[(t >> 6) * 2 + 1] = q; }
    __syncthreads();
    s = red[0] + red[2] + red[4] + red[6];
    q = red[1] + red[3] + red[5] + red[7];
    const float mean = s * (1.0f / EDIM);
    const float rs = rsqrtf(q * (1.0f / EDIM) - mean * mean + 1e-5f);
    f32x4 gg = ((const f32x4*)g)[t];
    f32x4 bb = ((const f32x4*)b)[t];
    bf16x4 o;
    #pragma unroll
    for (int j = 0; j < 4; ++j)
        o[j] = (bf16_t)gelu_exact((xf[j] - mean) * rs * gg[j] + bb[j]);
    ((bf16x4*)(out + row * EDIM))[t] = o;
}

__global__ void f2b(const float* __restrict__ in, bf16_t* __restrict__ out, long n4)
{
    long i = (long)blockIdx.x * blockDim.x + threadIdx.x;
    const long stride = (long)gridDim.x * blockDim.x;
    for (; i < n4; i += stride) {
        f32x4 v = ((const f32x4*)in)[i];
        bf16x4 o;
        #pragma unroll
        for (int j = 0; j < 4; ++j) o[j] = (bf16_t)v[j];
        ((bf16x4*)out)[i] = o;
    }
}

__global__ void tconv(const float* __restrict__ in, bf16_t* __restrict__ out)
{
    const long x = (long)blockIdx.x * 256 + threadIdx.x;
    const int k = (int)(x & (EDIM - 1));
    const int j = (int)(x >> 10);
    out[(long)j * EDIM + k] = (bf16_t)in[(long)k * EDIM + j];
}

__global__ __launch_bounds__(256)
void bcomb_k(const float* __restrict__ Wo, const float* __restrict__ bv,
             const float* __restrict__ bo, float* __restrict__ bc)
{
    const int i = blockIdx.x;
    const int t = threadIdx.x;
    f32x4 w = ((const f32x4*)(Wo + (long)i * EDIM))[t];
    f32x4 v = ((const f32x4*)bv)[t];
    float s = w[0]*v[0] + w[1]*v[1] + w[2]*v[2] + w[3]*v[3];
    #pragma unroll
    for (int off = 32; off; off >>= 1) s += __shfl_xor(s, off);
    __shared__ float red[4];
    if ((t & 63) == 0) red[t >> 6] = s;
    __syncthreads();
    if (t == 0) bc[i] = red[0] + red[1] + red[2] + red[3] + bo[i];
}

extern "C" void kernel_launch(void* const* d_in, const int* in_sizes, int n_in,
                              void* d_out, int out_size, void* d_ws, size_t ws_size,
                              hipStream_t stream)
{
    const float* lc_cls   = (const float*)d_in[0];
    const float* tab_emb  = (const float*)d_in[1];
    const float* ln_lc_g  = (const float*)d_in[2];
    const float* ln_lc_b  = (const float*)d_in[3];
    const float* ln_tab_g = (const float*)d_in[4];
    const float* ln_tab_b = (const float*)d_in[5];
    const float* alc_Wv   = (const float*)d_in[8];
    const float* alc_bv   = (const float*)d_in[11];
    const float* alc_Wo   = (const float*)d_in[12];
    const float* alc_bo   = (const float*)d_in[13];
    const float* atab_Wv  = (const float*)d_in[16];
    const float* atab_bv  = (const float*)d_in[19];
    const float* atab_Wo  = (const float*)d_in[20];
    const float* atab_bo  = (const float*)d_in[21];
    const float* flc_W1   = (const float*)d_in[22];
    const float* flc_b1   = (const float*)d_in[23];
    const float* flc_W2   = (const float*)d_in[24];
    const float* flc_b2   = (const float*)d_in[25];
    const float* ftab_W1  = (const float*)d_in[26];
    const float* ftab_b1  = (const float*)d_in[27];
    const float* ftab_W2  = (const float*)d_in[28];
    const float* ftab_b2  = (const float*)d_in[29];
    const float* on_g     = (const float*)d_in[30];
    const float* on_b     = (const float*)d_in[31];
    const float* c_W1     = (const float*)d_in[32];
    const float* c_b1     = (const float*)d_in[33];
    const float* c_ln_g   = (const float*)d_in[34];
    const float* c_ln_b   = (const float*)d_in[35];
    const float* c_W2     = (const float*)d_in[36];
    const float* c_b2     = (const float*)d_in[37];

    char* ws = (char*)d_ws;
    size_t woff = 0;
    auto walloc = [&](size_t bytes) {
        void* p = ws + woff;
        woff += (bytes + 255) & ~(size_t)255;
        return p;
    };
    // persistent bf16 weights (~38.2 MiB)
    bf16_t* Wc_lc  = (bf16_t*)walloc((size_t)EDIM * EDIM * 2);
    bf16_t* Wc_tab = (bf16_t*)walloc((size_t)EDIM * EDIM * 2);
    bf16_t* W1lc_b = (bf16_t*)walloc((size_t)FFD * EDIM * 2);
    bf16_t* W2lc_b = (bf16_t*)walloc((size_t)EDIM * FFD * 2);
    bf16_t* W1tab_b= (bf16_t*)walloc((size_t)FFD * EDIM * 2);
    bf16_t* W2tab_b= (bf16_t*)walloc((size_t)EDIM * FFD * 2);
    bf16_t* cW1_b  = (bf16_t*)walloc((size_t)EDIM * 2 * EDIM * 2);
    bf16_t* cW2_b  = (bf16_t*)walloc((size_t)NCD * EDIM * 2);
    float*  bc_lc  = (float*)walloc(EDIM * 4);
    float*  bc_tab = (float*)walloc(EDIM * 4);

    char* arena = ws + woff;
    const size_t arena_sz = (ws_size > woff) ? (ws_size - woff) : 0;

    // SB rows per super-chunk; arena need = SB*24576 bytes:
    //   cat (SB*4096, aliases lc_n|tab_n) | lc_x | tab_x | hbuf0 | hbuf1
    int SB = NB;
    while (SB > 256 && (size_t)SB * 24576 > arena_sz) SB >>= 1;
    if ((size_t)SB * 24576 > arena_sz) return;

    const size_t S2 = (size_t)SB * 2048;
    bf16_t* lc_n  = (bf16_t*)(arena);
    bf16_t* tab_n = (bf16_t*)(arena + S2);
    bf16_t* cat   = (bf16_t*)(arena);
    bf16_t* lc_x  = (bf16_t*)(arena + 2 * S2);
    bf16_t* tab_x = (bf16_t*)(arena + 3 * S2);
    bf16_t* hbuf0 = (bf16_t*)(arena + 4 * S2);
    bf16_t* hbuf1 = (bf16_t*)(arena + 8 * S2);
    bf16_t* tbuf  = lc_x;
    bf16_t* ubuf  = tab_x;

    // weight-prep temps (first 8 MiB of arena; used before activations exist)
    bf16_t* Wo_lc_b  = (bf16_t*)(arena);
    bf16_t* Wo_tab_b = (bf16_t*)(arena + (size_t)2 * 1024 * 1024);
    bf16_t* WvT_lc   = (bf16_t*)(arena + (size_t)4 * 1024 * 1024);
    bf16_t* WvT_tab  = (bf16_t*)(arena + (size_t)6 * 1024 * 1024);

    // ---- weight prep ----
    f2b<<<512, 256, 0, stream>>>(alc_Wo,  Wo_lc_b,  (long)EDIM * EDIM / 4);
    f2b<<<512, 256, 0, stream>>>(atab_Wo, Wo_tab_b, (long)EDIM * EDIM / 4);
    tconv<<<EDIM * EDIM / 256, 256, 0, stream>>>(alc_Wv,  WvT_lc);
    tconv<<<EDIM * EDIM / 256, 256, 0, stream>>>(atab_Wv, WvT_tab);
    f2b<<<2048, 256, 0, stream>>>(flc_W1,  W1lc_b,  (long)FFD * EDIM / 4);
    f2b<<<2048, 256, 0, stream>>>(flc_W2,  W2lc_b,  (long)EDIM * FFD / 4);
    f2b<<<2048, 256, 0, stream>>>(ftab_W1, W1tab_b, (long)FFD * EDIM / 4);
    f2b<<<2048, 256, 0, stream>>>(ftab_W2, W2tab_b, (long)EDIM * FFD / 4);
    f2b<<<1024, 256, 0, stream>>>(c_W1,    cW1_b,   (long)EDIM * 2 * EDIM / 4);
    f2b<<<32,   256, 0, stream>>>(c_W2,    cW2_b,   (long)NCD * EDIM / 4);
    bcomb_k<<<EDIM, 256, 0, stream>>>(alc_Wo,  alc_bv,  alc_bo,  bc_lc);
    bcomb_k<<<EDIM, 256, 0, stream>>>(atab_Wo, atab_bv, atab_bo, bc_tab);
    {   // Wcomb = Wo @ Wv (softmax over a single key == 1)
        GemmArgs ga = { Wo_lc_b, Wo_tab_b, WvT_lc, WvT_tab,
                        nullptr, nullptr, nullptr, nullptr, Wc_lc, Wc_tab };
        gemmP2<EPI_PLAIN><<<dim3(EDIM/128, (EDIM/256) * 2), 512, 0, stream>>>(
            ga, EDIM, 0, 0, EDIM, EDIM, EDIM);
    }

    // ---- batch loop ----
    for (long c0 = 0; c0 < NB; c0 += SB) {
        const float* lcI  = lc_cls  + c0 * EDIM;
        const float* tabI = tab_emb + c0 * EDIM;

        ln2_f32<<<dim3(SB, 2), 256, 0, stream>>>(
            lcI, ln_lc_g, ln_lc_b, lc_n, tabI, ln_tab_g, ln_tab_b, tab_n);

        {   // cross = resid + x_n @ Wcomb.T + bcomb
            GemmArgs ga = { tab_n, lc_n, Wc_lc, Wc_tab, bc_lc, bc_tab,
                            lcI, tabI, lc_x, tab_x };
            gemmP2<EPI_RESF32><<<dim3(EDIM/128, (SB/256) * 2), 512, 0, stream>>>(
                ga, EDIM, 0, 0, SB, EDIM, EDIM);
        }
        {   // FFN1: h = gelu(x @ W1.T + b1)
            GemmArgs ga = { lc_x, tab_x, W1lc_b, W1tab_b, flc_b1, ftab_b1,
                            nullptr, nullptr, hbuf0, hbuf1 };
            gemmP2<EPI_GELU><<<dim3(FFD/128, (SB/256) * 2), 512, 0, stream>>>(
                ga, FFD, 0, 0, SB, FFD, EDIM);
        }
        {   // FFN2: cat half = x + h @ W2.T + b2
            GemmArgs ga = { hbuf0, hbuf1, W2lc_b, W2tab_b, flc_b2, ftab_b2,
                            lc_x, tab_x, cat, cat };
            gemmP2<EPI_RESBF16><<<dim3(EDIM/128, (SB/256) * 2), 512, 0, stream>>>(
                ga, 2 * EDIM, 0, EDIM, SB, EDIM, FFD);
        }

        // output LN over 2048 (in place)
        ln_cat<<<SB, 256, 0, stream>>>(cat, on_g, on_b, cat);

        {   // classifier GEMM (K=2048, single side: gridDim.y == ny)
            GemmArgs ga = { cat, cat, cW1_b, cW1_b, c_b1, c_b1,
                            nullptr, nullptr, tbuf, tbuf };
            gemmP2<EPI_PLAIN><<<dim3(EDIM/128, SB/256), 512, 0, stream>>>(
                ga, EDIM, 0, 0, SB, EDIM, 2 * EDIM);
        }
        ln_gelu<<<SB, 256, 0, stream>>>(tbuf, c_ln_g, c_ln_b, ubuf);
        final_mfma<<<SB / 128, 256, 0, stream>>>(ubuf, cW2_b, c_b2,
                                                 (float*)d_out + c0 * NCD);
    }
}